// Round 1
// baseline (37483.524 us; speedup 1.0000x reference)
//
#include <hip/hip_runtime.h>
#include <hip/hip_bf16.h>

// Leaky 2-layer CTRNN, B=64 T=512 D_IN=256 H=1024 D_OUT=256, alpha=0.1.
// Strategy: persistent kernel over all T with per-phase device barrier.
//  - blocks 0..127  = layer0, computes t=p   (4 batch-groups x 32 h-chunks)
//  - blocks 128..255 = layer1, computes t=p-1 (pipelined: independent of L0[p])
//  - weights bf16 in LDS (XOR-swizzled 16B blocks), loaded ONCE, reused 512x
//  - fr exchange through d_out states regions (unique addr per t, no WAR)
//  - X0 = x@W_in0^T + b0 precomputed (bf16, ws); out GEMM at the end.

using u16 = unsigned short;

constexpr int Bsz = 64, Tlen = 512, DIN = 256, Hdim = 1024, DOUT = 256;
constexpr int NBLK = 256;   // persistent blocks (1 per CU; 128KB LDS forces 1/CU)
constexpr int NTHR = 512;   // 8 waves
constexpr int CH   = 32;    // h rows per chunk
constexpr int GB   = 16;    // batches per group

__device__ __forceinline__ u16 f2bf(float f) {            // fp32 -> bf16 RNE
  unsigned u = __float_as_uint(f);
  return (u16)((u + 0x7fffu + ((u >> 16) & 1u)) >> 16);
}
__device__ __forceinline__ float bflo(unsigned u) { return __uint_as_float(u << 16); }
__device__ __forceinline__ float bfhi(unsigned u) { return __uint_as_float(u & 0xffff0000u); }

// monotonic device-scope barrier: all NBLK blocks arrive; spin until count>=target
__device__ __forceinline__ void gbarrier(unsigned* cnt, unsigned target) {
  __syncthreads();
  if (threadIdx.x == 0) {
    __threadfence();  // agent fence: push our states writes to LLC
    __hip_atomic_fetch_add(cnt, 1u, __ATOMIC_ACQ_REL, __HIP_MEMORY_SCOPE_AGENT);
    unsigned v = __hip_atomic_load(cnt, __ATOMIC_ACQUIRE, __HIP_MEMORY_SCOPE_AGENT);
    while (v < target) {
      __builtin_amdgcn_s_sleep(2);
      v = __hip_atomic_load(cnt, __ATOMIC_ACQUIRE, __HIP_MEMORY_SCOPE_AGENT);
    }
  }
  __syncthreads();
}

// dot of LDS weight row (bf16, swizzled) with 1024 fp32 values from global.
// kstart: absolute k offset within the LDS row (0 or 1024).
__device__ __forceinline__ float dot1024(const u16* __restrict__ wrow, int kstart,
                                         const float* __restrict__ fr, int h_off) {
  float acc = 0.f;
#pragma unroll 4
  for (int k0 = 0; k0 < 1024; k0 += 8) {
    const int kb = (kstart + k0) >> 3;                     // 16B block index in row
    const uint4 wb = *(const uint4*)(wrow + ((kb ^ h_off) << 3));
    const float4 f0 = *(const float4*)(fr + k0);
    const float4 f1 = *(const float4*)(fr + k0 + 4);
    acc = fmaf(bflo(wb.x), f0.x, acc);
    acc = fmaf(bfhi(wb.x), f0.y, acc);
    acc = fmaf(bflo(wb.y), f0.z, acc);
    acc = fmaf(bfhi(wb.y), f0.w, acc);
    acc = fmaf(bflo(wb.z), f1.x, acc);
    acc = fmaf(bfhi(wb.z), f1.y, acc);
    acc = fmaf(bflo(wb.w), f1.z, acc);
    acc = fmaf(bfhi(wb.w), f1.w, acc);
  }
  return acc;
}

__global__ void __launch_bounds__(NTHR)
rnn_recurrent(const float* __restrict__ Wrec0, const float* __restrict__ Wrec1,
              const float* __restrict__ Win1,  const float* __restrict__ b1,
              const __hip_bfloat16* __restrict__ X0,
              float* __restrict__ states0, float* __restrict__ states1,
              unsigned* __restrict__ bar) {
  extern __shared__ u16 smW[];   // L1: [32][2048] bf16 = 128KB ; L0 uses [32][1024]
  const int bid = blockIdx.x;
  const int tid = threadIdx.x;
  const bool isL1 = (bid >= NBLK / 2);
  const int r  = bid & (NBLK / 2 - 1);
  const int g  = r >> 5;            // batch group 0..3
  const int c  = r & 31;            // h chunk 0..31
  const int hb = c * CH;
  const int h_off = tid & (CH - 1); // 0..31
  const int b2 = tid >> 5;          // 0..15
  const int b  = g * GB + b2;
  const int h  = hb + h_off;

  const int rowlen = isL1 ? 2048 : 1024;
  // Stage weight slice -> LDS bf16, XOR-swizzle 16B blocks: block kb stored at kb^h
  for (int e = tid; e < CH * rowlen; e += NTHR) {
    const int hr = e / rowlen;
    const int k  = e - hr * rowlen;
    float wv;
    if (!isL1)          wv = Wrec0[(size_t)(hb + hr) * Hdim + k];
    else if (k < 1024)  wv = Wrec1[(size_t)(hb + hr) * Hdim + k];
    else                wv = Win1 [(size_t)(hb + hr) * Hdim + (k - 1024)];
    const int kb = k >> 3, ko = k & 7;
    smW[hr * rowlen + (((kb ^ hr) << 3) | ko)] = f2bf(wv);
  }
  const float b1h = isL1 ? b1[h] : 0.f;
  const u16* wrow = smW + h_off * rowlen;
  float v = 0.f;
  __syncthreads();

  unsigned target = NBLK;
  for (int p = 0; p <= Tlen; ++p) {
    if (!isL1) {
      if (p < Tlen) {
        const int t = p;
        float acc = 0.f;
        if (t > 0)
          acc = dot1024(wrow, 0, states0 + ((size_t)b * Tlen + (t - 1)) * Hdim, h_off);
        acc += __bfloat162float(X0[((size_t)b * Tlen + t) * Hdim + h]);  // x@Win0^T + b0
        v = 0.9f * v + 0.1f * acc;
        states0[((size_t)b * Tlen + t) * Hdim + h] = fmaxf(v, 0.f);
      }
    } else {
      if (p >= 1) {
        const int t = p - 1;
        float acc = b1h;
        if (t > 0)
          acc += dot1024(wrow, 0, states1 + ((size_t)b * Tlen + (t - 1)) * Hdim, h_off);
        acc += dot1024(wrow, 1024, states0 + ((size_t)b * Tlen + t) * Hdim, h_off);
        v = 0.9f * v + 0.1f * acc;
        states1[((size_t)b * Tlen + t) * Hdim + h] = fmaxf(v, 0.f);
      }
    }
    if (p < Tlen) { gbarrier(bar, target); target += NBLK; }
  }
}

// C[n,m] = sum_k A[n,k]*Bm[m,k] + bias[m]; 64x64 tile, fp32, out fp32 or bf16
template <bool OUT_BF16>
__global__ void __launch_bounds__(256)
gemm_nt(const float* __restrict__ A, const float* __restrict__ Bm,
        const float* __restrict__ bias, void* __restrict__ Cout,
        int N, int M, int K) {
  __shared__ float As[32][68];  // [k][n], pad to 17x16B rows
  __shared__ float Bs[32][68];  // [k][m]
  const int tid = threadIdx.x;
  const int tx = tid & 15, ty = tid >> 4;
  const int n0 = blockIdx.x * 64, m0 = blockIdx.y * 64;
  float acc[4][4] = {};
  for (int k0 = 0; k0 < K; k0 += 32) {
#pragma unroll
    for (int l = 0; l < 2; ++l) {
      const int idx = tid + l * 256;
      const int row = idx >> 3;
      const int col = (idx & 7) << 2;
      const float4 av = *(const float4*)&A[(size_t)(n0 + row) * K + k0 + col];
      As[col + 0][row] = av.x; As[col + 1][row] = av.y;
      As[col + 2][row] = av.z; As[col + 3][row] = av.w;
      const float4 bv = *(const float4*)&Bm[(size_t)(m0 + row) * K + k0 + col];
      Bs[col + 0][row] = bv.x; Bs[col + 1][row] = bv.y;
      Bs[col + 2][row] = bv.z; Bs[col + 3][row] = bv.w;
    }
    __syncthreads();
#pragma unroll
    for (int k = 0; k < 32; ++k) {
      float a[4], bb[4];
      *(float4*)a  = *(const float4*)&As[k][ty * 4];
      *(float4*)bb = *(const float4*)&Bs[k][tx * 4];
#pragma unroll
      for (int i = 0; i < 4; ++i)
#pragma unroll
        for (int j = 0; j < 4; ++j) acc[i][j] = fmaf(a[i], bb[j], acc[i][j]);
    }
    __syncthreads();
  }
#pragma unroll
  for (int i = 0; i < 4; ++i) {
    const size_t n = n0 + ty * 4 + i;
#pragma unroll
    for (int j = 0; j < 4; ++j) {
      const int m = m0 + tx * 4 + j;
      const float val = acc[i][j] + (bias ? bias[m] : 0.f);
      if (OUT_BF16) ((__hip_bfloat16*)Cout)[n * M + m] = __float2bfloat16(val);
      else          ((float*)Cout)[n * M + m] = val;
    }
  }
}

extern "C" void kernel_launch(void* const* d_in, const int* in_sizes, int n_in,
                              void* d_out, int out_size, void* d_ws, size_t ws_size,
                              hipStream_t stream) {
  const float* x     = (const float*)d_in[0];
  const float* Win0  = (const float*)d_in[1];
  const float* Wrec0 = (const float*)d_in[2];
  const float* b0    = (const float*)d_in[3];
  const float* Win1  = (const float*)d_in[4];
  const float* Wrec1 = (const float*)d_in[5];
  const float* b1    = (const float*)d_in[6];
  const float* Wout  = (const float*)d_in[7];
  const float* bout  = (const float*)d_in[8];

  float* out     = (float*)d_out;
  float* states0 = out + (size_t)Bsz * Tlen * DOUT;
  float* states1 = states0 + (size_t)Bsz * Tlen * Hdim;

  unsigned* bar = (unsigned*)d_ws;
  __hip_bfloat16* X0 = (__hip_bfloat16*)((char*)d_ws + 256);
  const size_t need = 256 + (size_t)Bsz * Tlen * Hdim * sizeof(__hip_bfloat16);
  if (ws_size < need) return;  // can't run without X0 scratch

  hipMemsetAsync(d_ws, 0, 256, stream);  // zero barrier counter (ws is poisoned)

  // X0[b*T+t, h] = x[b,t,:] @ W_in0^T + b0   (bf16, hoisted out of the scan)
  gemm_nt<true><<<dim3((Bsz * Tlen) / 64, Hdim / 64), 256, 0, stream>>>(
      x, Win0, b0, (void*)X0, Bsz * Tlen, Hdim, DIN);

  hipFuncSetAttribute((const void*)rnn_recurrent,
                      hipFuncAttributeMaxDynamicSharedMemorySize, CH * 2048 * 2);
  rnn_recurrent<<<NBLK, NTHR, CH * 2048 * 2, stream>>>(
      Wrec0, Wrec1, Win1, b1, X0, states0, states1, bar);

  // output = states1 @ W_out^T + b_out
  gemm_nt<false><<<dim3((Bsz * Tlen) / 64, DOUT / 64), 256, 0, stream>>>(
      states1, Wout, bout, (void*)out, Bsz * Tlen, DOUT, Hdim);
}

// Round 2
// 22535.431 us; speedup vs baseline: 1.6633x; 1.6633x over previous
//
#include <hip/hip_runtime.h>
#include <hip/hip_bf16.h>

// Leaky 2-layer CTRNN, B=64 T=512 D_IN=256 H=1024 D_OUT=256, alpha=0.1.
// Round 2: persistent kernel, 256 blocks (1/CU forced via 84KB dyn-LDS).
//  - fp32 weights in LDS (no bf16 unpack), stored once device-wide:
//      L0 block c: Wrec0 rows [8c,8c+8);  L1 block c: Wrec1 + Win1 rows.
//  - thread=(h_off=tid&7, b=tid>>3): all 64 batches per block; wave=8h x 8b
//    -> ds_read_b128 serves 8 distinct rows (128B, bank-staggered, no conflict)
//  - v_pk_fma_f32 via ext_vector float2 + __builtin_elementwise_fma
//  - barrier: sc1 (agent-relaxed) state stores -> no wbl2; tree arrival
//    (32 padded leaves -> root), RELAXED spin, ONE acquire fence at exit.

using v2f = __attribute__((ext_vector_type(2))) float;

constexpr int Bsz = 64, Tlen = 512, DIN = 256, Hdim = 1024, DOUT = 256;
constexpr int NBLK = 256;           // persistent, 1 per CU
constexpr int NTHR = 512;           // 8 waves
constexpr int CH = 8;               // h rows per block
constexpr int RS = Hdim + 4;        // LDS row stride (floats): 4112B -> +4 banks/row

__device__ __forceinline__ void gbarrier(unsigned* bar, unsigned phase) {
  __builtin_amdgcn_s_waitcnt(0);            // every thread drains its sc1 stores
  __syncthreads();
  if (threadIdx.x == 0) {
    unsigned* leaf = bar + 32 + (blockIdx.x & 31) * 32;   // 128B-padded leaves
    unsigned old = __hip_atomic_fetch_add(leaf, 1u, __ATOMIC_RELAXED,
                                          __HIP_MEMORY_SCOPE_AGENT);
    if ((old & 7u) == 7u)                   // 8th arrival at this leaf this phase
      __hip_atomic_fetch_add(bar, 1u, __ATOMIC_RELAXED, __HIP_MEMORY_SCOPE_AGENT);
    while (__hip_atomic_load(bar, __ATOMIC_RELAXED, __HIP_MEMORY_SCOPE_AGENT) <
           phase * 32u)
      __builtin_amdgcn_s_sleep(4);
    __builtin_amdgcn_fence(__ATOMIC_ACQUIRE, "agent");  // one buffer_inv: drop stale L2
  }
  __syncthreads();
}

// dot(weight row in LDS, fr[0..1023] in global) with v_pk_fma_f32
__device__ __forceinline__ float dotH(const float* __restrict__ wrow,
                                      const float* __restrict__ fr) {
  v2f a0 = {0.f, 0.f}, a1 = {0.f, 0.f}, a2 = {0.f, 0.f}, a3 = {0.f, 0.f};
#pragma unroll 4
  for (int k = 0; k < Hdim; k += 8) {
    const float4 w0 = *(const float4*)(wrow + k);
    const float4 w1 = *(const float4*)(wrow + k + 4);
    const float4 f0 = *(const float4*)(fr + k);
    const float4 f1 = *(const float4*)(fr + k + 4);
    a0 = __builtin_elementwise_fma((v2f){w0.x, w0.y}, (v2f){f0.x, f0.y}, a0);
    a1 = __builtin_elementwise_fma((v2f){w0.z, w0.w}, (v2f){f0.z, f0.w}, a1);
    a2 = __builtin_elementwise_fma((v2f){w1.x, w1.y}, (v2f){f1.x, f1.y}, a2);
    a3 = __builtin_elementwise_fma((v2f){w1.z, w1.w}, (v2f){f1.z, f1.w}, a3);
  }
  a0 += a1; a2 += a3; a0 += a2;
  return a0.x + a0.y;
}

__global__ void __launch_bounds__(NTHR)
rnn_recurrent(const float* __restrict__ Wrec0, const float* __restrict__ Wrec1,
              const float* __restrict__ Win1,  const float* __restrict__ b1,
              const __hip_bfloat16* __restrict__ X0,
              float* __restrict__ states0, float* __restrict__ states1,
              unsigned* __restrict__ bar) {
  extern __shared__ float smW[];  // L0: [8][RS]; L1: [16][RS] (rec rows 0-7, in1 rows 8-15)
  const int bid = blockIdx.x, tid = threadIdx.x;
  const bool isL1 = bid >= NBLK / 2;
  const int c = bid & (NBLK / 2 - 1);       // h chunk 0..127
  const int h_off = tid & (CH - 1);         // 0..7
  const int b = tid >> 3;                   // 0..63
  const int h = c * CH + h_off;

  const int nrows = isL1 ? 2 * CH : CH;
  for (int e = tid; e < nrows * Hdim; e += NTHR) {
    const int r = e >> 10, k = e & (Hdim - 1);
    float w;
    if (!isL1)      w = Wrec0[(size_t)(c * CH + r) * Hdim + k];
    else if (r < CH) w = Wrec1[(size_t)(c * CH + r) * Hdim + k];
    else             w = Win1[(size_t)(c * CH + r - CH) * Hdim + k];
    smW[r * RS + k] = w;
  }
  const float bias1 = isL1 ? b1[h] : 0.f;
  const float* wrowA = smW + h_off * RS;           // rec weights row
  const float* wrowB = smW + (h_off + CH) * RS;    // in1 weights row (L1 only)
  const size_t bbase = (size_t)b * Tlen * Hdim;
  const float* rd_rec = (isL1 ? states1 : states0) + bbase;
  const float* rd_in  = states0 + bbase;           // L1 only
  float*       wr     = (isL1 ? states1 : states0) + bbase + h;
  const __hip_bfloat16* x0p = X0 + bbase + h;
  float v = 0.f;
  __syncthreads();

  unsigned phase = 1;
  for (int p = 0; p <= Tlen; ++p) {
    if (!isL1) {
      if (p < Tlen) {  // layer 0 computes t = p
        float acc = __bfloat162float(x0p[(size_t)p * Hdim]);
        if (p > 0) acc += dotH(wrowA, rd_rec + (size_t)(p - 1) * Hdim);
        v = 0.9f * v + 0.1f * acc;
        __hip_atomic_store(wr + (size_t)p * Hdim, fmaxf(v, 0.f),
                           __ATOMIC_RELAXED, __HIP_MEMORY_SCOPE_AGENT);
      }
    } else if (p >= 1) {  // layer 1 computes t = p-1
      const int t = p - 1;
      float acc = bias1 + dotH(wrowB, rd_in + (size_t)t * Hdim);
      if (t > 0) acc += dotH(wrowA, rd_rec + (size_t)(t - 1) * Hdim);
      v = 0.9f * v + 0.1f * acc;
      __hip_atomic_store(wr + (size_t)t * Hdim, fmaxf(v, 0.f),
                         __ATOMIC_RELAXED, __HIP_MEMORY_SCOPE_AGENT);
    }
    if (p < Tlen) { gbarrier(bar, phase); ++phase; }
  }
}

// C[n,m] = sum_k A[n,k]*Bm[m,k] + bias[m]; 64x64 tile, fp32, out fp32 or bf16
template <bool OUT_BF16>
__global__ void __launch_bounds__(256)
gemm_nt(const float* __restrict__ A, const float* __restrict__ Bm,
        const float* __restrict__ bias, void* __restrict__ Cout,
        int N, int M, int K) {
  __shared__ float As[32][68];
  __shared__ float Bs[32][68];
  const int tid = threadIdx.x;
  const int tx = tid & 15, ty = tid >> 4;
  const int n0 = blockIdx.x * 64, m0 = blockIdx.y * 64;
  float acc[4][4] = {};
  for (int k0 = 0; k0 < K; k0 += 32) {
#pragma unroll
    for (int l = 0; l < 2; ++l) {
      const int idx = tid + l * 256;
      const int row = idx >> 3;
      const int col = (idx & 7) << 2;
      const float4 av = *(const float4*)&A[(size_t)(n0 + row) * K + k0 + col];
      As[col + 0][row] = av.x; As[col + 1][row] = av.y;
      As[col + 2][row] = av.z; As[col + 3][row] = av.w;
      const float4 bv = *(const float4*)&Bm[(size_t)(m0 + row) * K + k0 + col];
      Bs[col + 0][row] = bv.x; Bs[col + 1][row] = bv.y;
      Bs[col + 2][row] = bv.z; Bs[col + 3][row] = bv.w;
    }
    __syncthreads();
#pragma unroll
    for (int k = 0; k < 32; ++k) {
      float a[4], bb[4];
      *(float4*)a  = *(const float4*)&As[k][ty * 4];
      *(float4*)bb = *(const float4*)&Bs[k][tx * 4];
#pragma unroll
      for (int i = 0; i < 4; ++i)
#pragma unroll
        for (int j = 0; j < 4; ++j) acc[i][j] = fmaf(a[i], bb[j], acc[i][j]);
    }
    __syncthreads();
  }
#pragma unroll
  for (int i = 0; i < 4; ++i) {
    const size_t n = n0 + ty * 4 + i;
#pragma unroll
    for (int j = 0; j < 4; ++j) {
      const int m = m0 + tx * 4 + j;
      const float val = acc[i][j] + (bias ? bias[m] : 0.f);
      if (OUT_BF16) ((__hip_bfloat16*)Cout)[n * M + m] = __float2bfloat16(val);
      else          ((float*)Cout)[n * M + m] = val;
    }
  }
}

extern "C" void kernel_launch(void* const* d_in, const int* in_sizes, int n_in,
                              void* d_out, int out_size, void* d_ws, size_t ws_size,
                              hipStream_t stream) {
  const float* x     = (const float*)d_in[0];
  const float* Win0  = (const float*)d_in[1];
  const float* Wrec0 = (const float*)d_in[2];
  const float* b0    = (const float*)d_in[3];
  const float* Win1  = (const float*)d_in[4];
  const float* Wrec1 = (const float*)d_in[5];
  const float* b1    = (const float*)d_in[6];
  const float* Wout  = (const float*)d_in[7];
  const float* bout  = (const float*)d_in[8];

  float* out     = (float*)d_out;
  float* states0 = out + (size_t)Bsz * Tlen * DOUT;
  float* states1 = states0 + (size_t)Bsz * Tlen * Hdim;

  unsigned* bar = (unsigned*)d_ws;  // root at [0]; 32 leaves at [32 + 32*i]
  __hip_bfloat16* X0 = (__hip_bfloat16*)((char*)d_ws + 16384);
  const size_t need = 16384 + (size_t)Bsz * Tlen * Hdim * sizeof(__hip_bfloat16);
  if (ws_size < need) return;

  hipMemsetAsync(d_ws, 0, 16384, stream);  // zero barrier counters

  // X0[b*T+t, h] = x[b,t,:] @ W_in0^T + b0   (bf16, hoisted out of the scan)
  gemm_nt<true><<<dim3((Bsz * Tlen) / 64, Hdim / 64), 256, 0, stream>>>(
      x, Win0, b0, (void*)X0, Bsz * Tlen, Hdim, DIN);

  // dyn-LDS: L1 needs 16*RS*4 = 65792B; request 84KB to force 1 block/CU
  const int lds_bytes = 86016;
  hipFuncSetAttribute((const void*)rnn_recurrent,
                      hipFuncAttributeMaxDynamicSharedMemorySize, lds_bytes);
  rnn_recurrent<<<NBLK, NTHR, lds_bytes, stream>>>(
      Wrec0, Wrec1, Win1, b1, X0, states0, states1, bar);

  // output = states1 @ W_out^T + b_out
  gemm_nt<false><<<dim3((Bsz * Tlen) / 64, DOUT / 64), 256, 0, stream>>>(
      states1, Wout, bout, (void*)out, Bsz * Tlen, DOUT, Hdim);
}